// Round 1
// baseline (11575.010 us; speedup 1.0000x reference)
//
#include <hip/hip_runtime.h>
#include <math.h>

// Seq2seq LSTM: 5-layer stack, HID=80, 336 enc steps + 48 dec steps.
// Batch-split persistent blocks: block handles NB=4 batch elements end-to-end,
// h/c state lives in LDS, no inter-block communication.
#define LAYERS 5
#define HID    80
#define GATES  320      // 4*HID, order [i|f|g|o]
#define INDIM  4
#define BATCH  512
#define SEQLEN 336
#define PREDLEN 48
#define NB     4        // batch elems per block
#define NTHR   320      // one thread per gate row; also == NB*HID for updates

static_assert(NTHR == GATES, "one thread per gate row");
static_assert(NTHR == NB * HID, "update mapping must cover NB*HID");

__device__ __forceinline__ float sigm(float v) { return 1.0f / (1.0f + __expf(-v)); }

// a0..a3 accumulate dot(w_row, h[nb]) for nb=0..3; k is the loop var.
#define DOT4_STEP(WROW, HBASE)                                                   \
    do {                                                                         \
        const float4 wv = *(const float4*)&(WROW)[k];                            \
        const float* hb = (HBASE);                                               \
        const float4 h0 = *(const float4*)&hb[0 * HID + k];                      \
        const float4 h1 = *(const float4*)&hb[1 * HID + k];                      \
        const float4 h2 = *(const float4*)&hb[2 * HID + k];                      \
        const float4 h3 = *(const float4*)&hb[3 * HID + k];                      \
        a0 += wv.x * h0.x + wv.y * h0.y + wv.z * h0.z + wv.w * h0.w;             \
        a1 += wv.x * h1.x + wv.y * h1.y + wv.z * h1.z + wv.w * h1.w;             \
        a2 += wv.x * h2.x + wv.y * h2.y + wv.z * h2.z + wv.w * h2.w;             \
        a3 += wv.x * h3.x + wv.y * h3.y + wv.z * h3.z + wv.w * h3.w;             \
    } while (0)

__global__ __launch_bounds__(NTHR, 1) void lstm_s2s(
    const float* __restrict__ x,    const float* __restrict__ ff,
    const float* __restrict__ eW0,  const float* __restrict__ eWih,
    const float* __restrict__ eWhh, const float* __restrict__ ebih,
    const float* __restrict__ ebhh,
    const float* __restrict__ dW0,  const float* __restrict__ dWih,
    const float* __restrict__ dWhh, const float* __restrict__ dbih,
    const float* __restrict__ dbhh,
    const float* __restrict__ fcW,  const float* __restrict__ fcb,
    float* __restrict__ out)
{
    __shared__ float sh[LAYERS][NB][HID];   // hidden state per layer
    __shared__ float sc[LAYERS][NB][HID];   // cell state per layer
    __shared__ float sg[NB][GATES];         // activated gates for current stage
    __shared__ float sx[NB][INDIM];         // current step input (enc x_t / dec feedback)

    const int tid = threadIdx.x;
    const int b0  = blockIdx.x * NB;

    for (int i = tid; i < LAYERS * NB * HID; i += NTHR) {
        (&sh[0][0][0])[i] = 0.0f;
        (&sc[0][0][0])[i] = 0.0f;
    }

    const int  g            = tid;                      // gate row this thread owns
    const bool is_tanh_gate = (g >= 2 * HID) && (g < 3 * HID);
    const int  unb          = tid / HID;                // update-phase mapping
    const int  uj           = tid % HID;

    for (int t = 0; t < SEQLEN + PREDLEN; ++t) {
        const bool   enc = (t < SEQLEN);
        const float* W0  = enc ? eW0  : dW0;
        const float* Wih = enc ? eWih : dWih;
        const float* Whh = enc ? eWhh : dWhh;
        const float* bi  = enc ? ebih : dbih;
        const float* bh  = enc ? ebhh : dbhh;

        if (enc && tid < NB * INDIM) {
            const int nb = tid / INDIM, k = tid % INDIM;
            sx[nb][k] = x[((size_t)(b0 + nb) * SEQLEN + t) * INDIM + k];
        }
        __syncthreads();   // sx staged (enc) / sx feedback + init state (dec, t=0)

        for (int l = 0; l < LAYERS; ++l) {
            const float bias = bi[l * GATES + g] + bh[l * GATES + g];
            float a0 = bias, a1 = bias, a2 = bias, a3 = bias;

            if (l == 0) {
                const float4 wv = *(const float4*)&W0[g * INDIM];
                a0 += wv.x * sx[0][0] + wv.y * sx[0][1] + wv.z * sx[0][2] + wv.w * sx[0][3];
                a1 += wv.x * sx[1][0] + wv.y * sx[1][1] + wv.z * sx[1][2] + wv.w * sx[1][3];
                a2 += wv.x * sx[2][0] + wv.y * sx[2][1] + wv.z * sx[2][2] + wv.w * sx[2][3];
                a3 += wv.x * sx[3][0] + wv.y * sx[3][1] + wv.z * sx[3][2] + wv.w * sx[3][3];
            } else {
                const float* w = &Wih[((size_t)(l - 1) * GATES + g) * HID];
                #pragma unroll 10
                for (int k = 0; k < HID; k += 4) DOT4_STEP(w, &sh[l - 1][0][0]);
            }
            {
                const float* w = &Whh[((size_t)l * GATES + g) * HID];
                #pragma unroll 10
                for (int k = 0; k < HID; k += 4) DOT4_STEP(w, &sh[l][0][0]);
            }

            const float v0 = is_tanh_gate ? tanhf(a0) : sigm(a0);
            const float v1 = is_tanh_gate ? tanhf(a1) : sigm(a1);
            const float v2 = is_tanh_gate ? tanhf(a2) : sigm(a2);
            const float v3 = is_tanh_gate ? tanhf(a3) : sigm(a3);
            sg[0][g] = v0;
            sg[1][g] = v1;
            sg[2][g] = v2;
            sg[3][g] = v3;
            __syncthreads();   // gates ready

            {
                const float iv = sg[unb][uj];
                const float fv = sg[unb][uj + HID];
                const float gv = sg[unb][uj + 2 * HID];
                const float ov = sg[unb][uj + 3 * HID];
                const float cn = fv * sc[l][unb][uj] + iv * gv;
                const float hn = ov * tanhf(cn);
                sc[l][unb][uj] = cn;
                sh[l][unb][uj] = hn;
            }
            __syncthreads();   // h/c updated before next stage reads them
        }

        if (!enc) {
            const int td = t - SEQLEN;
            if (tid < NB) {
                float s = fcb[0];
                #pragma unroll
                for (int j = 0; j < HID; j += 4) {
                    const float4 wv = *(const float4*)&fcW[j];
                    const float4 hv = *(const float4*)&sh[LAYERS - 1][tid][j];
                    s += wv.x * hv.x + wv.y * hv.y + wv.z * hv.z + wv.w * hv.w;
                }
                out[(size_t)(b0 + tid) * PREDLEN + td] = s;
                sx[tid][0] = s;                       // feedback: next input feature 0
            } else if (tid >= 64 && tid < 64 + NB * 3) {
                const int q = tid - 64;
                const int nb = q / 3, k = q % 3;
                sx[nb][k + 1] = ff[((size_t)(b0 + nb) * PREDLEN + td) * 3 + k];
            }
            // top-of-loop __syncthreads() covers these sx writes
        }
    }
}

extern "C" void kernel_launch(void* const* d_in, const int* in_sizes, int n_in,
                              void* d_out, int out_size, void* d_ws, size_t ws_size,
                              hipStream_t stream) {
    const float* x    = (const float*)d_in[0];
    const float* ff   = (const float*)d_in[1];
    const float* eW0  = (const float*)d_in[2];
    const float* eWih = (const float*)d_in[3];
    const float* eWhh = (const float*)d_in[4];
    const float* ebih = (const float*)d_in[5];
    const float* ebhh = (const float*)d_in[6];
    const float* dW0  = (const float*)d_in[7];
    const float* dWih = (const float*)d_in[8];
    const float* dWhh = (const float*)d_in[9];
    const float* dbih = (const float*)d_in[10];
    const float* dbhh = (const float*)d_in[11];
    const float* fcW  = (const float*)d_in[12];
    const float* fcb  = (const float*)d_in[13];

    lstm_s2s<<<BATCH / NB, NTHR, 0, stream>>>(
        x, ff, eW0, eWih, eWhh, ebih, ebhh,
        dW0, dWih, dWhh, dbih, dbhh, fcW, fcb, (float*)d_out);
}